// Round 11
// baseline (156.631 us; speedup 1.0000x reference)
//
#include <hip/hip_runtime.h>
#include <hip/hip_bf16.h>

#define B_ 32
#define T_ 2048
#define D_ 1024
#define A_ 128
#define NSLICE 16   // t-slices (blocks per b)
#define NCH 8       // 16-t chunks per slice

typedef __attribute__((ext_vector_type(8))) short bf16x8;
typedef __attribute__((ext_vector_type(4))) float f32x4;

static __device__ __forceinline__ unsigned short f2bf(float f) {
  union { float f; unsigned u; } v; v.f = f;
  unsigned r = v.u + 0x7FFFu + ((v.u >> 16) & 1u);
  return (unsigned short)(r >> 16);
}

// packed f32x2 -> bf16x2 (RNE); compiler emits v_cvt_pk_bf16_f32
static __device__ __forceinline__ unsigned cvt2u(float lo, float hi) {
  __hip_bfloat162 h2 = __float22bfloat162_rn(make_float2(lo, hi));
  unsigned u;
  __builtin_memcpy(&u, &h2, 4);
  return u;
}

// lgkm-only barrier: LDS visibility without draining vmcnt (st/B loads are
// reg-destined; their consumption is enforced by compiler-counted vmcnt at use)
static __device__ __forceinline__ void barrier_lds() {
  asm volatile("s_waitcnt lgkmcnt(0)\n\ts_barrier" ::: "memory");
}

// ---------------- prep: Wt[a][d] = bf16(Ws[d][a]) ----------------
__global__ __launch_bounds__(256) void k_prep(const float* __restrict__ Ws,
                                              unsigned short* __restrict__ Wt) {
  int i = blockIdx.x * 256 + threadIdx.x;  // coalesced write
  int a = i >> 10, d = i & 1023;
  Wt[i] = f2bf(Ws[(size_t)d * A_ + a]);
}

// ---------------- fused: scores -> exp -> weighted x accumulation ----------------
// grid (16, 32): blockIdx.x = t-slice (128 t), blockIdx.y = b. 512 thr (8 waves).
// LDS only 33.6 KB -> 2 blocks/CU co-resident: block A's barrier-serialized phases
// overlap block B's (m114 co-scheduling) — the r10 structure's idle-pipe fix.
// No W in registers/LDS (r4-r9: 256KB W = entire VGPR budget at any blocksize, and
// >160KB LDS): B-frags stream from L2-resident Wt (256 KB, zero over-fetch).
// x accumulated in f32 from STAGING REGISTERS (thread owns one t-row, 32 d); each
// thread computes its own e=expf(row-sum) from sc_part broadcast (no e barrier).
#define LDRB 1032  // bf16 row stride in shorts (2064 B): +16B pad
#define RSTR 516   // f32 stride of epilogue reduce buffer (aliases ab)

__global__ __launch_bounds__(512) void k_fused(const float* __restrict__ x,
                                               const unsigned short* __restrict__ Wt,
                                               const float* __restrict__ bs,
                                               const float* __restrict__ us,
                                               float* __restrict__ part,
                                               float* __restrict__ Zp) {
  __shared__ __align__(16) char smem[16 * LDRB * 2];  // 33,024 B: ab / epilogue red
  __shared__ float sc_part[16 * 8];
  __shared__ float zred[16];
  unsigned short* ab = (unsigned short*)smem;  // bf16 A-buffer [16][LDRB]
  float* red = (float*)smem;                   // epilogue reduce [16][RSTR]

  const int tid  = threadIdx.x;
  const int w    = tid >> 6;
  const int lane = tid & 63;
  const int lrow = lane & 15;
  const int g    = lane >> 4;
  const int sub  = blockIdx.x;
  const int b    = blockIdx.y;

  const int a_col = w * 16 + lrow;   // this wave's 16 a-columns
  const float bsv = bs[a_col];
  const float usv = us[a_col];
  const unsigned short* brow = Wt + (size_t)a_col * D_ + g * 8;  // B-frag base (L2)

  // staging: thread owns t-row srow; 8 float4 at d = scol + q*128 (+0..3)
  const int srow = w * 2 + (lane >> 5);
  const int scol = (lane & 31) * 4;
  const float* gx = x + ((size_t)b * T_ + (size_t)sub * 128) * D_;

  float4 st[8];
  f32x4 acc[8];
#pragma unroll
  for (int q = 0; q < 8; ++q) acc[q] = (f32x4)0.f;
  float zacc = 0.f;

#define ISSUE(ci)                                                                 \
  {                                                                               \
    const float* gp_ = gx + (size_t)(ci) * 16 * D_ + (size_t)srow * D_ + scol;    \
    _Pragma("unroll") for (int q = 0; q < 8; ++q)                                 \
        st[q] = *(const float4*)(gp_ + q * 128);                                  \
  }

#define WRITE_AB()                                                                \
  {                                                                               \
    _Pragma("unroll") for (int q = 0; q < 8; ++q) {                               \
      unsigned lo_ = cvt2u(st[q].x, st[q].y);                                     \
      unsigned hi_ = cvt2u(st[q].z, st[q].w);                                     \
      *(uint2*)(&ab[srow * LDRB + scol + q * 128]) = make_uint2(lo_, hi_);        \
    }                                                                             \
  }

  // prologue: chunk 0 -> regs -> ab
  ISSUE(0);
  WRITE_AB();
  barrier_lds();

  for (int i = 0; i < NCH; ++i) {
    // ---- phase 1: GEMM z[16t][16a] over K=1024 (A from ab, B from L2 Wt) ----
    // opaque copy of brow: blocks LICM from hoisting the 32 loop-invariant
    // B-loads out of the chunk loop into 128 registers (r4's spill mechanism)
    const unsigned short* bp = brow;
    asm volatile("" : "+v"(bp));
    f32x4 accm = (f32x4)0.f;
    const unsigned short* arow = ab + lrow * LDRB + g * 8;
#pragma unroll
    for (int kt = 0; kt < 32; ++kt) {
      bf16x8 af = *(const bf16x8*)(arow + kt * 32);
      bf16x8 bf = *(const bf16x8*)(bp + kt * 32);
      accm = __builtin_amdgcn_mfma_f32_16x16x32_bf16(af, bf, accm, 0, 0, 0);
    }

    // per-wave score partial: sum over this wave's 16 a of us*tanh(z+bs)
    // C layout: col = lane&15 (a), row = g*4 + r (t)
#pragma unroll
    for (int r = 0; r < 4; ++r) {
      float p = usv * tanhf(accm[r] + bsv);
#pragma unroll
      for (int o = 1; o < 16; o <<= 1) p += __shfl_xor(p, o, 64);
      if (lrow == 0) sc_part[(g * 4 + r) * 8 + w] = p;
    }
    barrier_lds();  // sc_part complete; all ab reads of chunk i complete

    // ---- phase 2: own-row e; exact f32 accumulate from staging registers ----
    // |score| <= ||us||_1 ~ 9 => expf without max-shift is safe in f32
    {
      float s_ = 0.f;
#pragma unroll
      for (int j = 0; j < 8; ++j) s_ += sc_part[srow * 8 + j];  // LDS broadcast
      const float e = expf(s_);
      zacc += e;
#pragma unroll
      for (int q = 0; q < 8; ++q) {
        acc[q][0] = fmaf(e, st[q].x, acc[q][0]);
        acc[q][1] = fmaf(e, st[q].y, acc[q][1]);
        acc[q][2] = fmaf(e, st[q].z, acc[q][2]);
        acc[q][3] = fmaf(e, st[q].w, acc[q][3]);
      }
    }

    // ---- phase 3: load + stage chunk i+1 (st now dead; co-resident block
    // covers the exposed load latency) ----
    if (i + 1 < NCH) {
      ISSUE(i + 1);
      WRITE_AB();     // waits counted vmcnt on its own loads only
      barrier_lds();  // ab(i+1) visible for next GEMM
    }
  }

  // ---- epilogue: combine 16 row-owners per d via red (aliases ab) ----
  if ((lane & 31) == 0) zred[srow] = zacc;  // one writer per t-row
#pragma unroll
  for (int h = 0; h < 2; ++h) {  // two 512-d halves (red = 16x516 f32 = 33 KB)
#pragma unroll
    for (int q = 0; q < 4; ++q)
      *(f32x4*)(&red[srow * RSTR + scol + q * 128]) = acc[h * 4 + q];
    barrier_lds();
    float s_ = 0.f;
#pragma unroll
    for (int r = 0; r < 16; ++r) s_ += red[r * RSTR + tid];
    part[((size_t)sub * B_ + b) * D_ + h * 512 + tid] = s_;
    if (h == 0) {
      if (tid == 0) {
        float Z = 0.f;
#pragma unroll
        for (int r = 0; r < 16; ++r) Z += zred[r];
        Zp[b * NSLICE + sub] = Z;
      }
      barrier_lds();  // red reads done before half-1 writes
    }
  }
#undef ISSUE
#undef WRITE_AB
}

// ---------------- reduce 16 slice-partials, divide by Z ----------------
__global__ __launch_bounds__(256) void k_reduce(const float* __restrict__ part,
                                                const float* __restrict__ Zp,
                                                float* __restrict__ out) {
  const int i = blockIdx.x * 256 + threadIdx.x;  // 0..32767
  const int b = i >> 10, d = i & 1023;
  float zs = 0.f;
#pragma unroll
  for (int s = 0; s < NSLICE; ++s) zs += Zp[b * NSLICE + s];
  float acc = 0.f;
#pragma unroll
  for (int s = 0; s < NSLICE; ++s) acc += part[((size_t)s * B_ + b) * D_ + d];
  out[i] = acc / zs;
}

extern "C" void kernel_launch(void* const* d_in, const int* in_sizes, int n_in,
                              void* d_out, int out_size, void* d_ws, size_t ws_size,
                              hipStream_t stream) {
  const float* x  = (const float*)d_in[0];
  const float* Ws = (const float*)d_in[1];
  const float* bs = (const float*)d_in[2];
  const float* us = (const float*)d_in[3];
  float* out = (float*)d_out;

  char* ws = (char*)d_ws;
  unsigned short* Wt = (unsigned short*)ws;                     // 256 KB
  float* part = (float*)(ws + (256 << 10));                     // 2 MB
  float* Zp   = (float*)(ws + (256 << 10) + (2 << 20));         // 2 KB

  k_prep<<<512, 256, 0, stream>>>(Ws, Wt);
  k_fused<<<dim3(NSLICE, B_), 512, 0, stream>>>(x, Wt, bs, us, part, Zp);
  k_reduce<<<(B_ * D_) / 256, 256, 0, stream>>>(part, Zp, out);
}